// Round 1
// baseline (768.764 us; speedup 1.0000x reference)
//
#include <hip/hip_runtime.h>

#define NN 2048
#define WW 32            // u64 words per bitmask row
#define DD 512
#define MS 512           // super nodes
#define TGTM 1536        // merges = NN - MS
#define KEYMAX 0x3FFFFFu

__device__ __forceinline__ void atomicMin64(unsigned long long* p, unsigned long long v){
  unsigned long long old = *p;
  while (v < old){
    unsigned long long assumed = old;
    old = atomicCAS(p, assumed, v);
    if (old == assumed) break;
  }
}

// Build 2048-bit adjacency bitmasks, degrees, and init component labels.
__global__ void k_build_bits(const float* __restrict__ A, unsigned long long* __restrict__ bits,
                             unsigned* __restrict__ deg, unsigned* __restrict__ comp){
  int gid = blockIdx.x*blockDim.x + threadIdx.x;   // NN*WW threads
  int i = gid >> 5, w = gid & 31;
  const float* row = A + ((size_t)i << 11) + (w << 6);
  unsigned long long m = 0ull;
  for (int k = 0; k < 64; ++k) if (row[k] > 0.0f) m |= (1ull << k);
  bits[((size_t)i << 5) + w] = m;
  atomicAdd(&deg[i], (unsigned)__popcll(m));
  if (gid < NN) comp[gid] = (unsigned)gid;
}

// Full symmetric key matrix: key22 = round(inter * 2^22 / union), exact int math.
__global__ void k_keymat(const unsigned long long* __restrict__ bits,
                         const unsigned* __restrict__ deg, unsigned* __restrict__ keyM){
  __shared__ unsigned long long bi[64][33];   // +1 pad: avoid 32-way LDS bank conflicts
  __shared__ unsigned long long bj[64][33];
  __shared__ unsigned degi[64], degj[64];
  int ib = blockIdx.x, jb = blockIdx.y;
  int t = threadIdx.x;
  for (int idx = t; idx < 64*32; idx += 256){
    int r = idx >> 5, w = idx & 31;
    bi[r][w] = bits[(((size_t)(ib*64 + r)) << 5) + w];
    bj[r][w] = bits[(((size_t)(jb*64 + r)) << 5) + w];
  }
  if (t < 64){ degi[t] = deg[ib*64 + t]; degj[t] = deg[jb*64 + t]; }
  __syncthreads();
  for (int p = t; p < 4096; p += 256){
    int ii = p >> 6, jj = p & 63;
    int i = ib*64 + ii, j = jb*64 + jj;
    unsigned key = 0u;
    if (i != j){
      unsigned inter = 0;
      #pragma unroll
      for (int w = 0; w < 32; ++w) inter += (unsigned)__popcll(bi[ii][w] & bj[jj][w]);
      unsigned b = degi[ii] + degj[jj] - inter;
      if (b != 0u){
        unsigned long long num = (((unsigned long long)inter) << 22) + (b >> 1);
        unsigned long long q = num / b;
        key = (q > (unsigned long long)KEYMAX) ? KEYMAX : (unsigned)q;
      }
    }
    keyM[((size_t)i << 11) + j] = key;
  }
}

// Per-node best outgoing edge (min 44-bit val) — one wave per row.
__global__ void k_best_node(const unsigned* __restrict__ keyM, const unsigned* __restrict__ comp,
                            unsigned long long* __restrict__ node_best){
  int gt = blockIdx.x*blockDim.x + threadIdx.x;
  int i = gt >> 6, lane = gt & 63;
  unsigned ci = comp[i];
  const unsigned* row = keyM + ((size_t)i << 11);
  unsigned long long best = ~0ull;
  for (int j = lane; j < NN; j += 64){
    if (j == i) continue;
    if (comp[j] == ci) continue;
    unsigned kp = KEYMAX - row[j];
    unsigned a  = (i < j) ? (unsigned)i : (unsigned)j;
    unsigned b2 = (i < j) ? (unsigned)j : (unsigned)i;
    unsigned long long v = (((unsigned long long)kp) << 22) | (((unsigned long long)a) << 11) | b2;
    if (v < best) best = v;
  }
  for (int off = 32; off; off >>= 1){
    unsigned long long o = __shfl_xor(best, off);
    if (o < best) best = o;
  }
  if (lane == 0) node_best[i] = best;
}

// One Boruvka round: per-component best, hook, 2-cycle break, collect MSF edges,
// pointer-double, relabel. Single block.
__global__ void k_merge(const unsigned long long* __restrict__ node_best,
                        unsigned* __restrict__ comp,
                        unsigned long long* __restrict__ msf, unsigned* __restrict__ msf_cnt){
  __shared__ unsigned long long cbest[NN];
  __shared__ unsigned nxtA[NN], nxtB[NN];
  int t = threadIdx.x;
  for (int c = t; c < NN; c += 256) cbest[c] = ~0ull;
  __syncthreads();
  for (int i = t; i < NN; i += 256) atomicMin64(&cbest[comp[i]], node_best[i]);
  __syncthreads();
  for (int c = t; c < NN; c += 256) nxtA[c] = (unsigned)c;
  __syncthreads();
  for (int c = t; c < NN; c += 256){
    unsigned long long v = cbest[c];
    if (v != ~0ull){
      unsigned a = (unsigned)((v >> 11) & 2047u), b = (unsigned)(v & 2047u);
      unsigned la = comp[a], lb = comp[b];
      nxtA[c] = (la == (unsigned)c) ? lb : la;
    }
  }
  __syncthreads();
  for (int c = t; c < NN; c += 256){
    unsigned o = nxtA[c];
    if (o != (unsigned)c && nxtA[o] == (unsigned)c && (unsigned)c < o) nxtA[c] = (unsigned)c;
  }
  __syncthreads();
  for (int c = t; c < NN; c += 256){
    if (nxtA[c] != (unsigned)c){
      unsigned idx = atomicAdd(msf_cnt, 1u);
      if (idx < (unsigned)NN) msf[idx] = cbest[c];
    }
  }
  __syncthreads();
  unsigned* s1 = nxtA; unsigned* s2 = nxtB;
  for (int r = 0; r < 11; ++r){
    for (int c = t; c < NN; c += 256) s2[c] = s1[s1[c]];
    __syncthreads();
    unsigned* tmp = s1; s1 = s2; s2 = tmp;
  }
  for (int i = t; i < NN; i += 256) comp[i] = s1[comp[i]];
}

// Sort the 2047 MSF edges, take first TGTM, connected components, labels/sizes/scale.
__global__ void k_final(const unsigned long long* __restrict__ msf, const unsigned* __restrict__ msf_cnt,
                        unsigned* __restrict__ labels_g, float* __restrict__ scale_g){
  __shared__ unsigned long long ed[NN];      // later reused as fo/plab
  __shared__ unsigned long long cbest[NN];   // later reused as sizes/scanT
  __shared__ unsigned lab[NN], nxtA[NN], nxtB[NN];
  int t = threadIdx.x;
  unsigned cnt = msf_cnt[0]; if (cnt > (unsigned)NN) cnt = NN;
  for (int i = t; i < NN; i += 256) ed[i] = (i < (int)cnt) ? msf[i] : ~0ull;
  __syncthreads();
  // bitonic sort ascending (44-bit vals unique; pads ~0 sort last)
  for (unsigned k = 2; k <= (unsigned)NN; k <<= 1)
    for (unsigned j = k >> 1; j > 0; j >>= 1){
      for (int i = t; i < NN; i += 256){
        unsigned l = ((unsigned)i) ^ j;
        if (l > (unsigned)i){
          bool up = ((((unsigned)i) & k) == 0u);
          unsigned long long x = ed[i], y = ed[l];
          if ((x > y) == up){ ed[i] = y; ed[l] = x; }
        }
      }
      __syncthreads();
    }
  // CC of first TGTM edges via Boruvka-style hooking (guaranteed <=11 rounds)
  for (int i = t; i < NN; i += 256) lab[i] = (unsigned)i;
  __syncthreads();
  for (int round = 0; round < 11; ++round){
    for (int c = t; c < NN; c += 256) cbest[c] = ~0ull;
    __syncthreads();
    for (int e = t; e < TGTM; e += 256){
      unsigned long long v = ed[e];
      unsigned a = (unsigned)((v >> 11) & 2047u), b = (unsigned)(v & 2047u);
      unsigned la = lab[a], lb = lab[b];
      if (la != lb){ atomicMin64(&cbest[la], v); atomicMin64(&cbest[lb], v); }
    }
    __syncthreads();
    for (int c = t; c < NN; c += 256) nxtA[c] = (unsigned)c;
    __syncthreads();
    for (int c = t; c < NN; c += 256){
      unsigned long long v = cbest[c];
      if (v != ~0ull){
        unsigned a = (unsigned)((v >> 11) & 2047u), b = (unsigned)(v & 2047u);
        unsigned la = lab[a], lb = lab[b];
        nxtA[c] = (la == (unsigned)c) ? lb : la;
      }
    }
    __syncthreads();
    for (int c = t; c < NN; c += 256){
      unsigned o = nxtA[c];
      if (o != (unsigned)c && nxtA[o] == (unsigned)c && (unsigned)c < o) nxtA[c] = (unsigned)c;
    }
    __syncthreads();
    unsigned* s1 = nxtA; unsigned* s2 = nxtB;
    for (int r = 0; r < 11; ++r){
      for (int c = t; c < NN; c += 256) s2[c] = s1[s1[c]];
      __syncthreads();
      unsigned* tmp = s1; s1 = s2; s2 = tmp;
    }
    for (int i = t; i < NN; i += 256) lab[i] = s1[lab[i]];
    __syncthreads();
  }
  // labels = rank of class by min member; sizes; scale
  unsigned* fo    = (unsigned*)ed;
  unsigned* plab  = ((unsigned*)ed) + NN;
  unsigned* sizes = (unsigned*)cbest;
  unsigned* scanT = ((unsigned*)cbest) + 1024;
  for (int i = t; i < NN; i += 256) fo[i] = 0xFFFFFFFFu;
  __syncthreads();
  for (int i = t; i < NN; i += 256) atomicMin(&fo[lab[i]], (unsigned)i);
  __syncthreads();
  unsigned loc[8]; unsigned s = 0; int base = t*8;
  for (int k = 0; k < 8; ++k){
    int i = base + k;
    unsigned isf = (fo[lab[i]] == (unsigned)i) ? 1u : 0u;
    loc[k] = s; s += isf;
  }
  scanT[t] = s; __syncthreads();
  for (int off = 1; off < 256; off <<= 1){
    unsigned x = (t >= off) ? scanT[t-off] : 0u;
    __syncthreads();
    scanT[t] += x;
    __syncthreads();
  }
  unsigned excl = scanT[t] - s;
  for (int k = 0; k < 8; ++k) plab[base + k] = excl + loc[k];
  __syncthreads();
  for (int c = t; c < MS; c += 256) sizes[c] = 0u;
  __syncthreads();
  for (int i = t; i < NN; i += 256){
    unsigned L = plab[fo[lab[i]]];
    labels_g[i] = L;
    if (L < (unsigned)MS) atomicAdd(&sizes[L], 1u);
  }
  __syncthreads();
  for (int c = t; c < MS; c += 256) scale_g[c] = 1.0f / sqrtf((float)sizes[c] + 1e-10f);
}

__global__ void k_writeP(const unsigned* __restrict__ labels, const float* __restrict__ scale,
                         float* __restrict__ P){
  int i = blockIdx.x*blockDim.x + threadIdx.x;
  if (i < NN){ unsigned L = labels[i]; P[((size_t)i << 9) + L] = scale[L]; }
}

__global__ void k_accX(const float* __restrict__ X, const unsigned* __restrict__ labels,
                       const float* __restrict__ scale, float* __restrict__ Xc){
  int idx = blockIdx.x*blockDim.x + threadIdx.x;   // NN*DD
  int i = idx >> 9, d = idx & 511;
  unsigned L = labels[i];
  atomicAdd(&Xc[((size_t)L << 9) + d], X[idx] * scale[L]);
}

__global__ void k_accA(const float* __restrict__ A, const unsigned* __restrict__ labels,
                       const float* __restrict__ scale, float* __restrict__ Ac){
  int idx = blockIdx.x*blockDim.x + threadIdx.x;   // NN*NN
  float a = A[idx];
  if (a != 0.0f){
    int i = idx >> 11, j = idx & 2047;
    unsigned Li = labels[i], Lj = labels[j];
    atomicAdd(&Ac[((size_t)Li << 9) + Lj], a * scale[Li] * scale[Lj]);
  }
}

extern "C" void kernel_launch(void* const* d_in, const int* in_sizes, int n_in,
                              void* d_out, int out_size, void* d_ws, size_t ws_size,
                              hipStream_t stream) {
  const float* X = (const float*)d_in[0];
  const float* A = (const float*)d_in[1];
  float* out = (float*)d_out;
  char* ws = (char*)d_ws;
  // workspace layout (~17.4 MB)
  unsigned long long* bits     = (unsigned long long*)(ws + 0x000000);  // 512 KB
  unsigned*           deg      = (unsigned*)          (ws + 0x080000);  // 8 KB
  unsigned*           comp     = (unsigned*)          (ws + 0x082000);  // 8 KB
  unsigned long long* nodebest = (unsigned long long*)(ws + 0x084000);  // 16 KB
  unsigned long long* msf      = (unsigned long long*)(ws + 0x088000);  // 16 KB
  unsigned*           msfcnt   = (unsigned*)          (ws + 0x08C000);  // 4 B
  unsigned*           labels   = (unsigned*)          (ws + 0x08D000);  // 8 KB
  float*              scale    = (float*)             (ws + 0x08F000);  // 2 KB
  unsigned*           keyM     = (unsigned*)          (ws + 0x090000);  // 16 MB

  hipMemsetAsync(deg, 0, NN*sizeof(unsigned), stream);
  hipMemsetAsync(msfcnt, 0, sizeof(unsigned), stream);
  hipMemsetAsync(d_out, 0, (size_t)out_size*sizeof(float), stream);

  k_build_bits<<<(NN*WW)/256, 256, 0, stream>>>(A, bits, deg, comp);
  k_keymat<<<dim3(NN/64, NN/64), 256, 0, stream>>>(bits, deg, keyM);
  for (int r = 0; r < 11; ++r){
    k_best_node<<<(NN*64)/256, 256, 0, stream>>>(keyM, comp, nodebest);
    k_merge<<<1, 256, 0, stream>>>(nodebest, comp, msf, msfcnt);
  }
  k_final<<<1, 256, 0, stream>>>(msf, msfcnt, labels, scale);
  k_writeP<<<NN/256, 256, 0, stream>>>(labels, scale, out + 2*MS*MS);
  k_accX<<<(NN*DD)/256, 256, 0, stream>>>(X, labels, scale, out);
  k_accA<<<(NN*NN)/256, 256, 0, stream>>>(A, labels, scale, out + MS*MS);
}